// Round 3
// baseline (498.253 us; speedup 1.0000x reference)
//
#include <hip/hip_runtime.h>

typedef unsigned short u16;
typedef short bf16x8 __attribute__((ext_vector_type(8)));
typedef float f32x4  __attribute__((ext_vector_type(4)));

#define NN 64
#define DD 256
#define LL 4096
#define KK 64
#define CHUNK 512
#define LS 64
#define NSUB 8        // CHUNK / LS
#define NCH 8         // chunks per image
#define SSZ (KK*DD)   // 16384

__device__ __forceinline__ u16 f2bf(float f) {
  union { float f; unsigned int i; } v; v.f = f;
  return (u16)((v.i + 0x8000u) >> 16);   // round-half-up (quantization only)
}

__global__ void zero_ws_kernel(float* __restrict__ p, int n4) {
  int i = blockIdx.x * 256 + threadIdx.x;
  if (i < n4) ((f32x4*)p)[i] = (f32x4){0.f, 0.f, 0.f, 0.f};
}

// ---------------------------------------------------------------------------
// Main fused kernel. Stages RAW x as bf16 (norm folded into softmax scaling):
//   S[k,d] = sum_l (softmax[k,l] * rno[l]) * x[d,l],  A[k] = sum_l softmax[k,l]
// Per iter (64 columns): stage + shuffle-norms -> GEMM1 -> distributed softmax
// (no max pass; |logit*rno| <= ||W_k|| = 16) -> GEMM2. 4 barriers/iter.
// PARTIAL=true: plain stores to per-block slice; else atomicAdd into S[n].
// ---------------------------------------------------------------------------
template <bool PARTIAL>
__global__ __launch_bounds__(256, 2) void netvlad_main(
    const float* __restrict__ xg, const float* __restrict__ wg,
    float* __restrict__ Sg, float* __restrict__ Ag) {
  __shared__ u16  x_dl[DD * LS];    // raw x bf16, [d][l] (8 chunks/row, swizzled)
  __shared__ u16  x_ld[LS * DD];    // raw x^T bf16, [l][d] (32 chunks/row, swizzled)
  __shared__ u16  akl[KK * LS];     // a' = softmax*rno, [k][l] (8 chunks/row)
  __shared__ float pnw[4 * LS];     // per-wave norm partials [w][l]
  __shared__ float wsum[4 * LS];    // per-wave softmax-denominator partials [w][l]

  const int tid  = threadIdx.x;
  const int w    = tid >> 6;        // wave 0..3
  const int lane = tid & 63;
  const int quad = lane >> 4;
  const int l15  = lane & 15;
  const int dblk = tid >> 3;        // 0..31 (d-rows dblk*8..+8)
  const int lblk = tid & 7;         // 0..7  (cols lblk*8..+8)
  const int dw   = lane >> 3;       // dblk within wave
  const int n    = blockIdx.x >> 3;
  const int ch   = blockIdx.x & 7;

  // W fragments: wave w owns k-tile w.  A-frag: A[m=l15][kred=quad*8+j]
  bf16x8 aw[8];
  {
    const float* wp = wg + (w * 16 + l15) * DD + quad * 8;
#pragma unroll
    for (int s = 0; s < 8; ++s) {
      f32x4 wa = *(const f32x4*)(wp + s * 32);
      f32x4 wb = *(const f32x4*)(wp + s * 32 + 4);
      bf16x8 t;
#pragma unroll
      for (int j = 0; j < 4; ++j) { t[j] = (short)f2bf(wa[j]); t[j + 4] = (short)f2bf(wb[j]); }
      aw[s] = t;
    }
  }

  f32x4 acc2[16];
#pragma unroll
  for (int i = 0; i < 16; ++i) acc2[i] = (f32x4){0.f, 0.f, 0.f, 0.f};
  float regAk[4] = {0.f, 0.f, 0.f, 0.f};

  const float* xbase = xg + (size_t)n * DD * LL + ch * CHUNK;

  f32x4 ga[8], gb[8];
#pragma unroll
  for (int r = 0; r < 8; ++r) {
    const float* p = xbase + (size_t)(dblk * 8 + r) * LL + lblk * 8;
    ga[r] = *(const f32x4*)p;
    gb[r] = *(const f32x4*)(p + 4);
  }

  for (int it = 0; it < NSUB; ++it) {
    // ---- phase A: norm partials (shuffle-reduced), bf16 convert, stage LDS
    float pj[8];
#pragma unroll
    for (int j = 0; j < 8; ++j) pj[j] = 0.f;
#pragma unroll
    for (int r = 0; r < 8; ++r)
#pragma unroll
      for (int j = 0; j < 4; ++j) {
        pj[j]     += ga[r][j] * ga[r][j];
        pj[j + 4] += gb[r][j] * gb[r][j];
      }
#pragma unroll
    for (int o = 8; o <= 32; o <<= 1)
#pragma unroll
      for (int j = 0; j < 8; ++j) pj[j] += __shfl_xor(pj[j], o);
    if (dw == 0) {   // lanes 0..7: write this wave's d-quarter partials for 8 cols
      *(f32x4*)&pnw[w * 64 + lblk * 8]     = (f32x4){pj[0], pj[1], pj[2], pj[3]};
      *(f32x4*)&pnw[w * 64 + lblk * 8 + 4] = (f32x4){pj[4], pj[5], pj[6], pj[7]};
    }

    u16 xn[8][8];
#pragma unroll
    for (int r = 0; r < 8; ++r)
#pragma unroll
      for (int j = 0; j < 4; ++j) {
        xn[r][j]     = f2bf(ga[r][j]);
        xn[r][j + 4] = f2bf(gb[r][j]);
      }
#pragma unroll
    for (int r = 0; r < 8; ++r) {          // [d][l]
      bf16x8 row;
#pragma unroll
      for (int j = 0; j < 8; ++j) row[j] = (short)xn[r][j];
      *(bf16x8*)&x_dl[(dblk * 8 + r) * 64 + ((lblk ^ r) * 8)] = row;
    }
#pragma unroll
    for (int j = 0; j < 8; ++j) {          // [l][d] (register transpose)
      bf16x8 col;
#pragma unroll
      for (int r = 0; r < 8; ++r) col[r] = (short)xn[r][j];
      int lam = lblk * 8 + j;
      *(bf16x8*)&x_ld[lam * 256 + ((dblk ^ (lam & 31)) * 8)] = col;
    }

    if (it + 1 < NSUB) {                   // prefetch next sub-tile
      const float* p = xbase + (it + 1) * LS;
#pragma unroll
      for (int r = 0; r < 8; ++r) {
        const float* q = p + (size_t)(dblk * 8 + r) * LL + lblk * 8;
        ga[r] = *(const f32x4*)q;
        gb[r] = *(const f32x4*)(q + 4);
      }
    }
    __syncthreads();                       // B1

    // ---- phase B: GEMM1 (unnormalized logits), scale by rno, exp, wave sums
    f32x4 acc1[4];
#pragma unroll
    for (int lt = 0; lt < 4; ++lt) acc1[lt] = (f32x4){0.f, 0.f, 0.f, 0.f};
#pragma unroll
    for (int s = 0; s < 8; ++s) {
#pragma unroll
      for (int lt = 0; lt < 4; ++lt) {
        int lam = lt * 16 + l15;
        bf16x8 b = *(const bf16x8*)&x_ld[lam * 256 + (((s * 4 + quad) ^ (lam & 31)) * 8)];
        acc1[lt] = __builtin_amdgcn_mfma_f32_16x16x32_bf16(aw[s], b, acc1[lt], 0, 0, 0);
      }
    }
    float rno[4], e[4][4], psum[4];
#pragma unroll
    for (int lt = 0; lt < 4; ++lt) {
      int l = lt * 16 + l15;
      float s = pnw[l] + pnw[64 + l] + pnw[128 + l] + pnw[192 + l];
      rno[lt] = rsqrtf(fmaxf(s, 1e-24f));
      float ps = 0.f;
#pragma unroll
      for (int r = 0; r < 4; ++r) { e[lt][r] = __expf(acc1[lt][r] * rno[lt]); ps += e[lt][r]; }
      ps += __shfl_xor(ps, 16);
      ps += __shfl_xor(ps, 32);            // sum over this wave's 16 k's
      psum[lt] = ps;
    }
    float pw = quad == 0 ? psum[0] : quad == 1 ? psum[1] : quad == 2 ? psum[2] : psum[3];
    wsum[w * 64 + quad * 16 + l15] = pw;
    __syncthreads();                       // B2

    // ---- phase C: finish softmax, write a' = softmax*rno to akl
#pragma unroll
    for (int lt = 0; lt < 4; ++lt) {
      int l = lt * 16 + l15;
      float rs = 1.f / (wsum[l] + wsum[64 + l] + wsum[128 + l] + wsum[192 + l]);
      float rr = rs * rno[lt];
#pragma unroll
      for (int r = 0; r < 4; ++r) {
        float sm = e[lt][r] * rs;
        regAk[r] += sm;
        int k = w * 16 + quad * 4 + r;
        akl[k * 64 + (((l >> 3) ^ (k & 7)) * 8) + (l & 7)] = f2bf(e[lt][r] * rr);
      }
    }
    __syncthreads();                       // B3

    // ---- phase D: GEMM2  S[k,d] += sum_l a'[k,l] * x[d,l]
#pragma unroll
    for (int s = 0; s < 2; ++s) {
      int kk = w * 16 + l15;
      bf16x8 aA = *(const bf16x8*)&akl[kk * 64 + (((s * 4 + quad) ^ (kk & 7)) * 8)];
#pragma unroll
      for (int dt = 0; dt < 16; ++dt) {
        int d = dt * 16 + l15;
        bf16x8 bX = *(const bf16x8*)&x_dl[d * 64 + (((s * 4 + quad) ^ (d & 7)) * 8)];
        acc2[dt] = __builtin_amdgcn_mfma_f32_16x16x32_bf16(aA, bX, acc2[dt], 0, 0, 0);
      }
    }
    __syncthreads();                       // B4
  }

  // ---- epilogue
  if (PARTIAL) {
    float* Sp = Sg + (size_t)blockIdx.x * SSZ;
#pragma unroll
    for (int dt = 0; dt < 16; ++dt)
#pragma unroll
      for (int r = 0; r < 4; ++r)
        Sp[(w * 16 + quad * 4 + r) * DD + dt * 16 + l15] = acc2[dt][r];
  } else {
    float* Sn = Sg + (size_t)n * SSZ;
#pragma unroll
    for (int dt = 0; dt < 16; ++dt)
#pragma unroll
      for (int r = 0; r < 4; ++r)
        atomicAdd(&Sn[(w * 16 + quad * 4 + r) * DD + dt * 16 + l15], acc2[dt][r]);
  }
#pragma unroll
  for (int o = 1; o <= 8; o <<= 1)
#pragma unroll
    for (int r = 0; r < 4; ++r) regAk[r] += __shfl_xor(regAk[r], o);
  if (l15 == 0) {
    if (PARTIAL) {
      float* Ap = Ag + (size_t)blockIdx.x * KK;
#pragma unroll
      for (int r = 0; r < 4; ++r) Ap[w * 16 + quad * 4 + r] = regAk[r];
    } else {
#pragma unroll
      for (int r = 0; r < 4; ++r) atomicAdd(&Ag[n * KK + w * 16 + quad * 4 + r], regAk[r]);
    }
  }
}

// ---------------------------------------------------------------------------
// Finalize: sum nsl slices, vlad = S - A*c, intra-norm, global norm, store.
// Coalesced f32x4 loads (lane = d/4); wave butterfly per-k reduction;
// v kept in registers between passes. One block per n; wave w -> k=w*16+i.
// ---------------------------------------------------------------------------
__global__ __launch_bounds__(256, 2) void netvlad_fin(
    const float* __restrict__ Sg, const float* __restrict__ Ag,
    const float* __restrict__ cg, float* __restrict__ outg, int nsl) {
  __shared__ float wtot[4];
  const int n = blockIdx.x, tid = threadIdx.x;
  const int w = tid >> 6, lane = tid & 63;
  const float* Sb = Sg + (size_t)n * nsl * SSZ;
  const float* Ab = Ag + (size_t)n * nsl * KK;

  f32x4 v[16];
  float rk[16];
  float tot = 0.f;
#pragma unroll
  for (int i = 0; i < 16; ++i) {
    const int k = w * 16 + i;
    float Ak = 0.f;
    for (int sl = 0; sl < nsl; ++sl) Ak += Ab[sl * KK + k];
    f32x4 s = (f32x4){0.f, 0.f, 0.f, 0.f};
    for (int sl = 0; sl < nsl; ++sl)
      s += *(const f32x4*)&Sb[(size_t)sl * SSZ + k * DD + lane * 4];
    f32x4 c4 = *(const f32x4*)&cg[k * DD + lane * 4];
    f32x4 t = s - Ak * c4;
    v[i] = t;
    float q = t[0] * t[0] + t[1] * t[1] + t[2] * t[2] + t[3] * t[3];
#pragma unroll
    for (int o = 1; o <= 32; o <<= 1) q += __shfl_xor(q, o);
    float r = 1.f / fmaxf(sqrtf(q), 1e-12f);
    rk[i] = r;
    tot += q * r * r;
  }
  if (lane == 0) wtot[w] = tot;
  __syncthreads();
  const float g = wtot[0] + wtot[1] + wtot[2] + wtot[3];
  const float gs = 1.f / fmaxf(sqrtf(g), 1e-12f);
#pragma unroll
  for (int i = 0; i < 16; ++i) {
    const int k = w * 16 + i;
    const float sc = rk[i] * gs;
    f32x4 o = v[i];
    o[0] *= sc; o[1] *= sc; o[2] *= sc; o[3] *= sc;
    *(f32x4*)&outg[(size_t)n * SSZ + k * DD + lane * 4] = o;
  }
}

extern "C" void kernel_launch(void* const* d_in, const int* in_sizes, int n_in,
                              void* d_out, int out_size, void* d_ws, size_t ws_size,
                              hipStream_t stream) {
  const float* x   = (const float*)d_in[0];
  const float* wgt = (const float*)d_in[1];
  const float* cen = (const float*)d_in[2];
  float* out = (float*)d_out;

  const size_t nblk = (size_t)NN * NCH;                      // 512
  const size_t need = nblk * SSZ * 4 + nblk * KK * 4;        // ~33.7 MB
  if (ws_size >= need) {
    float* Sp = (float*)d_ws;
    float* Ap = Sp + nblk * SSZ;
    hipLaunchKernelGGL((netvlad_main<true>), dim3(NN * NCH), dim3(256), 0, stream, x, wgt, Sp, Ap);
    hipLaunchKernelGGL(netvlad_fin, dim3(NN), dim3(256), 0, stream, Sp, Ap, cen, out, NCH);
  } else {
    float* S = (float*)d_ws;
    float* A = S + (size_t)NN * SSZ;
    const int n4 = (NN * SSZ + NN * KK) / 4;
    hipLaunchKernelGGL(zero_ws_kernel, dim3((n4 + 255) / 256), dim3(256), 0, stream, S, n4);
    hipLaunchKernelGGL((netvlad_main<false>), dim3(NN * NCH), dim3(256), 0, stream, x, wgt, S, A);
    hipLaunchKernelGGL(netvlad_fin, dim3(NN), dim3(256), 0, stream, S, A, cen, out, 1);
  }
}

// Round 5
// 397.464 us; speedup vs baseline: 1.2536x; 1.2536x over previous
//
#include <hip/hip_runtime.h>

typedef unsigned short u16;
typedef short bf16x8 __attribute__((ext_vector_type(8)));
typedef float f32x4  __attribute__((ext_vector_type(4)));

#define NN 64
#define DD 256
#define LL 4096
#define KK 64
#define CHUNK 512
#define SUB 16        // columns per DMA substep
#define NSTEP 32      // CHUNK / SUB
#define NCH 8         // chunks per image
#define SSZ (KK*DD)   // 16384
// padded LDS strides (elements)
#define XDL_S 40      // x_dl row stride (32 cols + pad)
#define XLD_S 264     // x_ld row stride (256 d + pad)
#define AKL_S 40      // akl row stride

__device__ __forceinline__ u16 f2bf(float f) {
  union { float f; unsigned int i; } v; v.f = f;
  return (u16)((v.i + 0x8000u) >> 16);   // round-half-up (quantization only)
}

// async global->LDS DMA, 16B per lane; LDS dest = wave-uniform base + lane*16.
// Both pointers must be addrspace-cast via an integer round-trip (direct
// ptr->ptr addrspace reinterpret_cast is rejected by clang).
__device__ __forceinline__ void load_lds16(const float* g, float* l) {
  auto gp = reinterpret_cast<const __attribute__((address_space(1))) unsigned int*>(
      reinterpret_cast<unsigned long long>(g));
  auto lp = reinterpret_cast<__attribute__((address_space(3))) unsigned int*>(
      reinterpret_cast<unsigned long long>(l));
  __builtin_amdgcn_global_load_lds(gp, lp, 16, 0, 0);
}

__global__ void zero_ws_kernel(float* __restrict__ p, int n4) {
  int i = blockIdx.x * 256 + threadIdx.x;
  if (i < n4) ((f32x4*)p)[i] = (f32x4){0.f, 0.f, 0.f, 0.f};
}

// ---------------------------------------------------------------------------
// Main fused kernel, async-DMA pipeline.
//   S[k,d] = sum_l (softmax[k,l]*rno[l]) * x[d,l],  A[k] = sum_l softmax[k,l]
// Per 16-col substep: DMA(s+1) -> norms+convert(s) -> B1 -> GEMM1+softmax ->
// B2 -> a' writes; every odd substep: B3 -> GEMM2 (K=32 over 32 cols) -> B4.
// Wave w DMAs d-rows w*64..w*64+63; consumption is one substep behind with a
// barrier between, so cross-wave visibility is safe.
// ---------------------------------------------------------------------------
template <bool PARTIAL>
__global__ __launch_bounds__(256, 2) void netvlad_main(
    const float* __restrict__ xg, const float* __restrict__ wg,
    float* __restrict__ Sg, float* __restrict__ Ag) {
  __shared__ __align__(16) float raw[2][DD * SUB];      // 2 x 16 KB fp32 ping-pong
  __shared__ __align__(16) u16  x_ld[SUB * XLD_S];      // [l][d] bf16, 16 rows
  __shared__ __align__(16) u16  x_dl[DD * XDL_S];       // [d][l] bf16, 32 cols
  __shared__ __align__(16) u16  akl[KK * AKL_S];        // a' bf16, 32 cols
  __shared__ float pnw[4][SUB];                         // per-wave norm partials
  __shared__ float wsum[4][SUB];                        // per-wave softmax partials

  const int tid  = threadIdx.x;
  const int w    = tid >> 6;
  const int lane = tid & 63;
  const int quad = lane >> 4;
  const int l15  = lane & 15;
  const int dblk = tid >> 3;        // 0..31 -> d rows dblk*8..+7
  const int lp   = tid & 7;         // col pair lp*2, lp*2+1 (within substep)
  const int n    = blockIdx.x >> 3;
  const int ch   = blockIdx.x & 7;

  // W fragments: wave w owns k-tile w.  A-frag: A[m=l15][kred=quad*8+j]
  bf16x8 aw[8];
  {
    const float* wp = wg + (w * 16 + l15) * DD + quad * 8;
#pragma unroll
    for (int s = 0; s < 8; ++s) {
      f32x4 wa = *(const f32x4*)(wp + s * 32);
      f32x4 wb = *(const f32x4*)(wp + s * 32 + 4);
      bf16x8 t;
#pragma unroll
      for (int j = 0; j < 4; ++j) { t[j] = (short)f2bf(wa[j]); t[j + 4] = (short)f2bf(wb[j]); }
      aw[s] = t;
    }
  }

  f32x4 acc2[16];
#pragma unroll
  for (int i = 0; i < 16; ++i) acc2[i] = (f32x4){0.f, 0.f, 0.f, 0.f};
  float regAk[4] = {0.f, 0.f, 0.f, 0.f};

  const float* xcol = xg + (size_t)n * DD * LL + (size_t)ch * CHUNK;
  // per-lane global offset within a 16-row DMA group: row = lane>>2, 16B chunk = lane&3
  const size_t goff = (size_t)(lane >> 2) * LL + (lane & 3) * 4;

  // ---- preload substep 0
  {
    const float* gs = xcol + (size_t)(w * 64) * LL + goff;
    float* lb = &raw[0][(w * 64) * SUB];
#pragma unroll
    for (int j = 0; j < 4; ++j)
      load_lds16(gs + (size_t)(j * 16) * LL, lb + j * 16 * SUB);
  }
  __syncthreads();

  for (int s = 0; s < NSTEP; ++s) {
    const int buf = s & 1;
    // ---- DMA next substep (drained by this substep's first barrier)
    if (s + 1 < NSTEP) {
      const float* gs = xcol + (s + 1) * SUB + (size_t)(w * 64) * LL + goff;
      float* lb = &raw[buf ^ 1][(w * 64) * SUB];
#pragma unroll
      for (int j = 0; j < 4; ++j)
        load_lds16(gs + (size_t)(j * 16) * LL, lb + j * 16 * SUB);
    }

    // ---- norms: wave w sums its d-quarter for 16 cols.
    // d = w*64 + quad + 4*i  => bank = (d*16+l15)&31 = lane&31: conflict-free.
    {
      const float* col = &raw[buf][(w * 64 + quad) * SUB + l15];
      float pj = 0.f;
#pragma unroll
      for (int i = 0; i < 16; ++i) { float v = col[i * 4 * SUB]; pj += v * v; }
      pj += __shfl_xor(pj, 16);
      pj += __shfl_xor(pj, 32);
      if (lane < 16) pnw[w][lane] = pj;
    }

    // ---- convert: 8 d-rows x 2 cols per thread -> x_dl + x_ld
    {
      const int labs = ((s & 1) << 4) + lp * 2;   // absolute col in 32-col pair
      const float* rb = &raw[buf][0];
      bf16x8 c0, c1;
#pragma unroll
      for (int r = 0; r < 8; ++r) {
        int d = dblk * 8 + r;
        float2 v = *(const float2*)(rb + d * SUB + lp * 2);
        u16 a = f2bf(v.x), b = f2bf(v.y);
        c0[r] = (short)a; c1[r] = (short)b;
        *(unsigned int*)&x_dl[d * XDL_S + labs] = (unsigned int)a | ((unsigned int)b << 16);
      }
      *(bf16x8*)&x_ld[(lp * 2)     * XLD_S + dblk * 8] = c0;
      *(bf16x8*)&x_ld[(lp * 2 + 1) * XLD_S + dblk * 8] = c1;
    }
    __syncthreads();   // B1: staging visible; DMA(s+1) drained

    // ---- GEMM1: logits[16k x 16l], K=256 over d
    f32x4 acc1 = (f32x4){0.f, 0.f, 0.f, 0.f};
#pragma unroll
    for (int s8 = 0; s8 < 8; ++s8) {
      bf16x8 b = *(const bf16x8*)&x_ld[l15 * XLD_S + s8 * 32 + quad * 8];
      acc1 = __builtin_amdgcn_mfma_f32_16x16x32_bf16(aw[s8], b, acc1, 0, 0, 0);
    }
    // softmax part 1: scale by rno, exp, per-wave k-sums
    float s4 = pnw[0][l15] + pnw[1][l15] + pnw[2][l15] + pnw[3][l15];
    float rno = rsqrtf(fmaxf(s4, 1e-24f));
    float e[4];
    float ps = 0.f;
#pragma unroll
    for (int r = 0; r < 4; ++r) { e[r] = __expf(acc1[r] * rno); ps += e[r]; }
    ps += __shfl_xor(ps, 16);
    ps += __shfl_xor(ps, 32);
    if (lane < 16) wsum[w][lane] = ps;
    __syncthreads();   // B2

    // ---- softmax part 2: a' = softmax * rno -> akl
    {
      float rs = 1.f / (wsum[0][l15] + wsum[1][l15] + wsum[2][l15] + wsum[3][l15]);
      float rr = rs * rno;
      int labs = ((s & 1) << 4) + l15;
#pragma unroll
      for (int r = 0; r < 4; ++r) {
        regAk[r] += e[r] * rs;
        akl[(w * 16 + quad * 4 + r) * AKL_S + labs] = f2bf(e[r] * rr);
      }
    }

    if (s & 1) {
      __syncthreads(); // B3: akl/x_dl (both 16-col halves) visible
      // ---- GEMM2: S[16k x 256d] += over 32 cols (K=32)
      const int kk = w * 16 + l15;
      bf16x8 aA = *(const bf16x8*)&akl[kk * AKL_S + quad * 8];
#pragma unroll
      for (int dt = 0; dt < 16; ++dt) {
        int d = dt * 16 + l15;
        bf16x8 bX = *(const bf16x8*)&x_dl[d * XDL_S + quad * 8];
        acc2[dt] = __builtin_amdgcn_mfma_f32_16x16x32_bf16(aA, bX, acc2[dt], 0, 0, 0);
      }
      __syncthreads(); // B4: GEMM2 done before next convert overwrites x_dl/akl
    }
  }

  // ---- epilogue
  if (PARTIAL) {
    float* Sp = Sg + (size_t)blockIdx.x * SSZ;
#pragma unroll
    for (int dt = 0; dt < 16; ++dt)
#pragma unroll
      for (int r = 0; r < 4; ++r)
        Sp[(w * 16 + quad * 4 + r) * DD + dt * 16 + l15] = acc2[dt][r];
  } else {
    float* Sn = Sg + (size_t)n * SSZ;
#pragma unroll
    for (int dt = 0; dt < 16; ++dt)
#pragma unroll
      for (int r = 0; r < 4; ++r)
        atomicAdd(&Sn[(w * 16 + quad * 4 + r) * DD + dt * 16 + l15], acc2[dt][r]);
  }
#pragma unroll
  for (int o = 1; o <= 8; o <<= 1)
#pragma unroll
    for (int r = 0; r < 4; ++r) regAk[r] += __shfl_xor(regAk[r], o);
  if (l15 == 0) {
    if (PARTIAL) {
      float* Ap = Ag + (size_t)blockIdx.x * KK;
#pragma unroll
      for (int r = 0; r < 4; ++r) Ap[w * 16 + quad * 4 + r] = regAk[r];
    } else {
#pragma unroll
      for (int r = 0; r < 4; ++r) atomicAdd(&Ag[n * KK + w * 16 + quad * 4 + r], regAk[r]);
    }
  }
}

// ---------------------------------------------------------------------------
// Finalize: sum NSL slices (compile-time, fully unrolled -> MLP), subtract
// A*c, intra-norm, global norm, store. One block per n; wave w -> k=w*16+i.
// ---------------------------------------------------------------------------
template <int NSL>
__global__ __launch_bounds__(256, 2) void netvlad_fin(
    const float* __restrict__ Sg, const float* __restrict__ Ag,
    const float* __restrict__ cg, float* __restrict__ outg) {
  __shared__ float wtot[4];
  const int n = blockIdx.x, tid = threadIdx.x;
  const int w = tid >> 6, lane = tid & 63;
  const float* Sb = Sg + (size_t)n * NSL * SSZ;
  const float* Ab = Ag + (size_t)n * NSL * KK;

  f32x4 v[16];
  float rk[16];
  float tot = 0.f;
#pragma unroll
  for (int i = 0; i < 16; ++i) {
    const int k = w * 16 + i;
    float Ak = 0.f;
#pragma unroll
    for (int sl = 0; sl < NSL; ++sl) Ak += Ab[sl * KK + k];
    f32x4 sacc = (f32x4){0.f, 0.f, 0.f, 0.f};
#pragma unroll
    for (int sl = 0; sl < NSL; ++sl)
      sacc += *(const f32x4*)&Sb[(size_t)sl * SSZ + k * DD + lane * 4];
    f32x4 c4 = *(const f32x4*)&cg[k * DD + lane * 4];
    f32x4 t = sacc - Ak * c4;
    v[i] = t;
    float q = t[0] * t[0] + t[1] * t[1] + t[2] * t[2] + t[3] * t[3];
#pragma unroll
    for (int o = 1; o <= 32; o <<= 1) q += __shfl_xor(q, o);
    float r = 1.f / fmaxf(sqrtf(q), 1e-12f);
    rk[i] = r;
    tot += q * r * r;
  }
  if (lane == 0) wtot[w] = tot;
  __syncthreads();
  const float g = wtot[0] + wtot[1] + wtot[2] + wtot[3];
  const float gs = 1.f / fmaxf(sqrtf(g), 1e-12f);
#pragma unroll
  for (int i = 0; i < 16; ++i) {
    const int k = w * 16 + i;
    const float sc = rk[i] * gs;
    f32x4 o = v[i];
    o[0] *= sc; o[1] *= sc; o[2] *= sc; o[3] *= sc;
    *(f32x4*)&outg[(size_t)n * SSZ + k * DD + lane * 4] = o;
  }
}

extern "C" void kernel_launch(void* const* d_in, const int* in_sizes, int n_in,
                              void* d_out, int out_size, void* d_ws, size_t ws_size,
                              hipStream_t stream) {
  const float* x   = (const float*)d_in[0];
  const float* wgt = (const float*)d_in[1];
  const float* cen = (const float*)d_in[2];
  float* out = (float*)d_out;

  const size_t nblk = (size_t)NN * NCH;                      // 512
  const size_t need = nblk * SSZ * 4 + nblk * KK * 4;        // ~33.7 MB
  if (ws_size >= need) {
    float* Sp = (float*)d_ws;
    float* Ap = Sp + nblk * SSZ;
    hipLaunchKernelGGL((netvlad_main<true>), dim3(NN * NCH), dim3(256), 0, stream, x, wgt, Sp, Ap);
    hipLaunchKernelGGL((netvlad_fin<NCH>), dim3(NN), dim3(256), 0, stream, Sp, Ap, cen, out);
  } else {
    float* S = (float*)d_ws;
    float* A = S + (size_t)NN * SSZ;
    const int n4 = (NN * SSZ + NN * KK) / 4;
    hipLaunchKernelGGL(zero_ws_kernel, dim3((n4 + 255) / 256), dim3(256), 0, stream, S, n4);
    hipLaunchKernelGGL((netvlad_main<false>), dim3(NN * NCH), dim3(256), 0, stream, x, wgt, S, A);
    hipLaunchKernelGGL((netvlad_fin<1>), dim3(NN), dim3(256), 0, stream, S, A, cen, out);
  }
}

// Round 6
// 394.139 us; speedup vs baseline: 1.2642x; 1.0084x over previous
//
#include <hip/hip_runtime.h>

typedef unsigned short u16;
typedef unsigned int u32;
typedef short bf16x8 __attribute__((ext_vector_type(8)));
typedef float f32x4  __attribute__((ext_vector_type(4)));

#define NN 64
#define DD 256
#define LL 4096
#define KK 64
#define CHUNK 512
#define SUB 32        // columns per substep
#define NSTEP 16      // CHUNK / SUB
#define NCH 8         // chunks per image
#define SSZ (KK*DD)   // 16384
// LDS strides in u16 elements; byte stride must be %16==0 for b128 access
#define XLD_S 264     // x_ld row stride (256 d + pad)
#define XDL_S 40      // x_dl row stride (32 cols + pad)
#define AKL_S 40      // akl row stride (32 cols + pad)

__device__ __forceinline__ u16 f2bf(float f) {
  union { float f; u32 i; } v; v.f = f;
  return (u16)((v.i + 0x8000u) >> 16);   // round-half-up (quantization only)
}

// LDS-only barrier: wait LDS ops, sync, but leave global loads (vmcnt) in
// flight across the barrier (CK block_sync_lds idiom). This is the whole
// point of this round: __syncthreads drains vmcnt(0) and kills streaming.
__device__ __forceinline__ void barrier_lds() {
  asm volatile("s_waitcnt lgkmcnt(0)\n\ts_barrier" ::: "memory");
}

__global__ void zero_ws_kernel(float* __restrict__ p, int n4) {
  int i = blockIdx.x * 256 + threadIdx.x;
  if (i < n4) ((f32x4*)p)[i] = (f32x4){0.f, 0.f, 0.f, 0.f};
}

// ---------------------------------------------------------------------------
// Main fused kernel, register-streaming pipeline.
//   S[k,d] = sum_l (softmax[k,l]*rno[l]) * x[d,l],  A[k] = sum_l softmax[k,l]
// Wave w owns d-rows w*64..w*64+63. Per 32-col substep: prefetch s+1 into the
// other register buffer (128B-contiguous per row, stays in flight across all
// barriers) -> norms+convert(s) -> B1 -> GEMM1+softmax p1 -> B2 -> softmax p2
// (akl) -> B3 -> GEMM2 (all 64 k x own 64 d) -> B4.
// ---------------------------------------------------------------------------
template <bool PARTIAL>
__global__ __launch_bounds__(256, 2) void netvlad_main(
    const float* __restrict__ xg, const float* __restrict__ wg,
    float* __restrict__ Sg, float* __restrict__ Ag) {
  __shared__ __align__(16) u16 x_ld[SUB * XLD_S];       // [l][d], cross-wave
  __shared__ __align__(16) u16 x_dl[4][64 * XDL_S];     // [w][d_local][l], wave-private
  __shared__ __align__(16) u16 akl[KK * AKL_S];         // a' = softmax*rno
  __shared__ float pnw[4][SUB];                         // per-wave norm partials
  __shared__ float wsum[4][SUB];                        // per-wave softmax partials

  const int tid  = threadIdx.x;
  const int w    = tid >> 6;
  const int lane = tid & 63;
  const int quad = lane >> 4;
  const int l15  = lane & 15;
  const int g    = lane >> 3;       // 0..7: row-group within wave's 64 rows
  const int c    = lane & 7;        // 0..7: 4-col group within the 32 cols
  const int n    = blockIdx.x >> 3;
  const int ch   = blockIdx.x & 7;

  // W fragments: wave w owns k-tile w for GEMM1. A-frag: A[m=l15][kred=quad*8+j]
  bf16x8 aw[8];
  {
    const float* wp = wg + (w * 16 + l15) * DD + quad * 8;
#pragma unroll
    for (int s = 0; s < 8; ++s) {
      f32x4 wa = *(const f32x4*)(wp + s * 32);
      f32x4 wb = *(const f32x4*)(wp + s * 32 + 4);
      bf16x8 t;
#pragma unroll
      for (int j = 0; j < 4; ++j) { t[j] = (short)f2bf(wa[j]); t[j + 4] = (short)f2bf(wb[j]); }
      aw[s] = t;
    }
  }

  f32x4 acc2[4][4];                 // [kt][dt]: k = kt*16+quad*4+r, d = w*64+dt*16+l15
#pragma unroll
  for (int a = 0; a < 4; ++a)
#pragma unroll
    for (int b = 0; b < 4; ++b) acc2[a][b] = (f32x4){0.f, 0.f, 0.f, 0.f};
  float regAk[4] = {0.f, 0.f, 0.f, 0.f};

  // thread's global base: rows w*64+g*8 .. +7 (via +i*LL), cols c*4..+3
  const float* xw = xg + (size_t)n * DD * LL + (size_t)(w * 64 + g * 8) * LL
                    + ch * CHUNK + c * 4;

  f32x4 buf0[8], buf1[8];
  // preload substep 0
#pragma unroll
  for (int i = 0; i < 8; ++i) buf0[i] = *(const f32x4*)(xw + (size_t)i * LL);

  auto step = [&](f32x4 (&cur)[8], f32x4 (&nxt)[8], int s) {
    // ---- prefetch substep s+1 (stays in flight across all 4 barriers)
    if (s + 1 < NSTEP) {
      const float* q = xw + (s + 1) * SUB;
#pragma unroll
      for (int i = 0; i < 8; ++i) nxt[i] = *(const f32x4*)(q + (size_t)i * LL);
    }

    // ---- norms: wave sums its 64 d-rows per column
    {
      f32x4 pj = (f32x4){0.f, 0.f, 0.f, 0.f};
#pragma unroll
      for (int i = 0; i < 8; ++i) pj += cur[i] * cur[i];
#pragma unroll
      for (int o = 8; o <= 32; o <<= 1)
#pragma unroll
        for (int j = 0; j < 4; ++j) pj[j] += __shfl_xor(pj[j], o);
      if (g == 0) *(f32x4*)&pnw[w][c * 4] = pj;
    }

    // ---- convert to bf16, stage x_dl (own quarter) + x_ld
    u16 xb[8][4];
#pragma unroll
    for (int i = 0; i < 8; ++i)
#pragma unroll
      for (int j = 0; j < 4; ++j) xb[i][j] = f2bf(cur[i][j]);
#pragma unroll
    for (int i = 0; i < 8; ++i) {       // x_dl: row g*8+i, cols c*4..+3 (b64)
      u32 lo = (u32)xb[i][0] | ((u32)xb[i][1] << 16);
      u32 hi = (u32)xb[i][2] | ((u32)xb[i][3] << 16);
      *(uint2*)&x_dl[w][(g * 8 + i) * XDL_S + c * 4] = make_uint2(lo, hi);
    }
#pragma unroll
    for (int j = 0; j < 4; ++j) {       // x_ld: row c*4+j, d-offset w*64+g*8 (b128)
      bf16x8 col;
#pragma unroll
      for (int i = 0; i < 8; ++i) col[i] = (short)xb[i][j];
      *(bf16x8*)&x_ld[(c * 4 + j) * XLD_S + w * 64 + g * 8] = col;
    }
    barrier_lds();   // B1

    // ---- GEMM1: logits 16k x 32l, K=256 over d
    f32x4 acc1[2];
    acc1[0] = (f32x4){0.f, 0.f, 0.f, 0.f};
    acc1[1] = (f32x4){0.f, 0.f, 0.f, 0.f};
#pragma unroll
    for (int s8 = 0; s8 < 8; ++s8)
#pragma unroll
      for (int lt = 0; lt < 2; ++lt) {
        bf16x8 b = *(const bf16x8*)&x_ld[(lt * 16 + l15) * XLD_S + s8 * 32 + quad * 8];
        acc1[lt] = __builtin_amdgcn_mfma_f32_16x16x32_bf16(aw[s8], b, acc1[lt], 0, 0, 0);
      }
    // softmax p1: scale by rno, exp, per-wave k-sums
    float rno[2], e[2][4], ps[2];
#pragma unroll
    for (int lt = 0; lt < 2; ++lt) {
      int col = lt * 16 + l15;
      float s4 = pnw[0][col] + pnw[1][col] + pnw[2][col] + pnw[3][col];
      rno[lt] = rsqrtf(fmaxf(s4, 1e-24f));
      float p = 0.f;
#pragma unroll
      for (int r = 0; r < 4; ++r) { e[lt][r] = __expf(acc1[lt][r] * rno[lt]); p += e[lt][r]; }
      p += __shfl_xor(p, 16);
      p += __shfl_xor(p, 32);
      ps[lt] = p;
    }
    if (quad < 2) wsum[w][quad * 16 + l15] = (quad == 0) ? ps[0] : ps[1];
    barrier_lds();   // B2

    // ---- softmax p2: a' = softmax * rno -> akl
#pragma unroll
    for (int lt = 0; lt < 2; ++lt) {
      int col = lt * 16 + l15;
      float rs = 1.f / (wsum[0][col] + wsum[1][col] + wsum[2][col] + wsum[3][col]);
      float rr = rs * rno[lt];
#pragma unroll
      for (int r = 0; r < 4; ++r) {
        regAk[r] += e[lt][r] * rs;
        akl[(w * 16 + quad * 4 + r) * AKL_S + col] = f2bf(e[lt][r] * rr);
      }
    }
    barrier_lds();   // B3

    // ---- GEMM2: all 64 k x own 64 d, K=32 cols
    bf16x8 bx[4];
#pragma unroll
    for (int dt = 0; dt < 4; ++dt)
      bx[dt] = *(const bf16x8*)&x_dl[w][(dt * 16 + l15) * XDL_S + quad * 8];
#pragma unroll
    for (int kt = 0; kt < 4; ++kt) {
      bf16x8 aA = *(const bf16x8*)&akl[(kt * 16 + l15) * AKL_S + quad * 8];
#pragma unroll
      for (int dt = 0; dt < 4; ++dt)
        acc2[kt][dt] = __builtin_amdgcn_mfma_f32_16x16x32_bf16(aA, bx[dt], acc2[kt][dt], 0, 0, 0);
    }
    barrier_lds();   // B4: protect x_ld/x_dl/akl/pnw before next substep
  };

#pragma unroll 1
  for (int sp = 0; sp < NSTEP / 2; ++sp) {
    step(buf0, buf1, 2 * sp);
    step(buf1, buf0, 2 * sp + 1);
  }

  // ---- epilogue
  if (PARTIAL) {
    float* Sp = Sg + (size_t)blockIdx.x * SSZ;
#pragma unroll
    for (int kt = 0; kt < 4; ++kt)
#pragma unroll
      for (int dt = 0; dt < 4; ++dt)
#pragma unroll
        for (int r = 0; r < 4; ++r)
          Sp[(kt * 16 + quad * 4 + r) * DD + w * 64 + dt * 16 + l15] = acc2[kt][dt][r];
  } else {
    float* Sn = Sg + (size_t)n * SSZ;
#pragma unroll
    for (int kt = 0; kt < 4; ++kt)
#pragma unroll
      for (int dt = 0; dt < 4; ++dt)
#pragma unroll
        for (int r = 0; r < 4; ++r)
          atomicAdd(&Sn[(kt * 16 + quad * 4 + r) * DD + w * 64 + dt * 16 + l15],
                    acc2[kt][dt][r]);
  }
#pragma unroll
  for (int o = 1; o <= 8; o <<= 1)
#pragma unroll
    for (int r = 0; r < 4; ++r) regAk[r] += __shfl_xor(regAk[r], o);
  if (l15 == 0) {
    if (PARTIAL) {
      float* Ap = Ag + (size_t)blockIdx.x * KK;
#pragma unroll
      for (int r = 0; r < 4; ++r) Ap[w * 16 + quad * 4 + r] = regAk[r];
    } else {
#pragma unroll
      for (int r = 0; r < 4; ++r) atomicAdd(&Ag[n * KK + w * 16 + quad * 4 + r], regAk[r]);
    }
  }
}

// ---------------------------------------------------------------------------
// Finalize: sum NSL slices (unrolled -> MLP), subtract A*c, intra-norm,
// global norm, store. One block per n; wave w -> k = w*16+i.
// ---------------------------------------------------------------------------
template <int NSL>
__global__ __launch_bounds__(256, 2) void netvlad_fin(
    const float* __restrict__ Sg, const float* __restrict__ Ag,
    const float* __restrict__ cg, float* __restrict__ outg) {
  __shared__ float wtot[4];
  const int n = blockIdx.x, tid = threadIdx.x;
  const int w = tid >> 6, lane = tid & 63;
  const float* Sb = Sg + (size_t)n * NSL * SSZ;
  const float* Ab = Ag + (size_t)n * NSL * KK;

  f32x4 v[16];
  float rk[16];
  float tot = 0.f;
#pragma unroll
  for (int i = 0; i < 16; ++i) {
    const int k = w * 16 + i;
    float Ak = 0.f;
#pragma unroll
    for (int sl = 0; sl < NSL; ++sl) Ak += Ab[sl * KK + k];
    f32x4 sacc = (f32x4){0.f, 0.f, 0.f, 0.f};
#pragma unroll
    for (int sl = 0; sl < NSL; ++sl)
      sacc += *(const f32x4*)&Sb[(size_t)sl * SSZ + k * DD + lane * 4];
    f32x4 c4 = *(const f32x4*)&cg[k * DD + lane * 4];
    f32x4 t = sacc - Ak * c4;
    v[i] = t;
    float q = t[0] * t[0] + t[1] * t[1] + t[2] * t[2] + t[3] * t[3];
#pragma unroll
    for (int o = 1; o <= 32; o <<= 1) q += __shfl_xor(q, o);
    float r = 1.f / fmaxf(sqrtf(q), 1e-12f);
    rk[i] = r;
    tot += q * r * r;
  }
  if (lane == 0) wtot[w] = tot;
  __syncthreads();
  const float gtot = wtot[0] + wtot[1] + wtot[2] + wtot[3];
  const float gs = 1.f / fmaxf(sqrtf(gtot), 1e-12f);
#pragma unroll
  for (int i = 0; i < 16; ++i) {
    const int k = w * 16 + i;
    const float sc = rk[i] * gs;
    f32x4 o = v[i];
    o[0] *= sc; o[1] *= sc; o[2] *= sc; o[3] *= sc;
    *(f32x4*)&outg[(size_t)n * SSZ + k * DD + lane * 4] = o;
  }
}

extern "C" void kernel_launch(void* const* d_in, const int* in_sizes, int n_in,
                              void* d_out, int out_size, void* d_ws, size_t ws_size,
                              hipStream_t stream) {
  const float* x   = (const float*)d_in[0];
  const float* wgt = (const float*)d_in[1];
  const float* cen = (const float*)d_in[2];
  float* out = (float*)d_out;

  const size_t nblk = (size_t)NN * NCH;                      // 512
  const size_t need = nblk * SSZ * 4 + nblk * KK * 4;        // ~33.7 MB
  if (ws_size >= need) {
    float* Sp = (float*)d_ws;
    float* Ap = Sp + nblk * SSZ;
    hipLaunchKernelGGL((netvlad_main<true>), dim3(NN * NCH), dim3(256), 0, stream, x, wgt, Sp, Ap);
    hipLaunchKernelGGL((netvlad_fin<NCH>), dim3(NN), dim3(256), 0, stream, Sp, Ap, cen, out);
  } else {
    float* S = (float*)d_ws;
    float* A = S + (size_t)NN * SSZ;
    const int n4 = (NN * SSZ + NN * KK) / 4;
    hipLaunchKernelGGL(zero_ws_kernel, dim3((n4 + 255) / 256), dim3(256), 0, stream, S, n4);
    hipLaunchKernelGGL((netvlad_main<false>), dim3(NN * NCH), dim3(256), 0, stream, x, wgt, S, A);
    hipLaunchKernelGGL((netvlad_fin<1>), dim3(NN), dim3(256), 0, stream, S, A, cen, out);
  }
}